// Round 3
// baseline (376.665 us; speedup 1.0000x reference)
//
#include <hip/hip_runtime.h>
#include <math.h>

#define BS 8
#define NPTS 16384
#define C 32
#define K 256
#define KNNK 16
#define NBINS 512
#define BINW 0.00025f
#define CAP 4096
#define NSPL 64          // point-splits per graph in k_logits

typedef float f32x4 __attribute__((ext_vector_type(4)));
typedef __bf16 bf16x8 __attribute__((ext_vector_type(8)));
union U16x8 { int4 i; bf16x8 v; unsigned short u[8]; };

// ---------------------------------------------------------------------------
// Phase 1: MFMA logit GEMM + exp + weighted position accumulation.
// Split-bf16: L = A_lo*B_hi + A_hi*B_lo + A_hi*B_hi (fp32 MFMA accum);
// verified: identical KNN sets vs fp32 path. Pooling head (W_pool) unused:
// its logit term is constant over n and cancels in the per-graph softmax.
// Block 0 additionally zeroes ccnt (workspace is poisoned each iteration;
// stream order makes it visible to k_cand).
// ---------------------------------------------------------------------------
__global__ __launch_bounds__(256, 2) void k_logits(
    const float* __restrict__ f, const float* __restrict__ pos,
    const float* __restrict__ Wr, float* __restrict__ partials,
    unsigned* __restrict__ ccnt) {
  int b = blockIdx.x >> 6;          // 64 blocks per graph
  int r = blockIdx.x & 63;
  int pbase = b * NPTS + r * 256;
  int t = threadIdx.x;
  int w = t >> 6, lane = t & 63;
  int h = w & 1, nh = w >> 1;
  int quad = lane >> 4, col = lane & 15;

  if (blockIdx.x == 0 && t < BS) ccnt[t] = 0;

  __shared__ float4 posLDS[256];
  __shared__ float4 fm[2][256];

  // stage pos chunk (256 pts x 12 B) -> padded float4 via LDS repack
  float* rawf = (float*)&fm[0][0];
  if (t < 192) ((float4*)rawf)[t] = ((const float4*)(pos + (size_t)pbase * 3))[t];
  __syncthreads();
  float4 myp = make_float4(rawf[t * 3], rawf[t * 3 + 1], rawf[t * 3 + 2], 0.f);
  __syncthreads();
  posLDS[t] = myp;

  // B fragments for this wave's kp-half (8 tiles), direct fp32 load + split.
  U16x8 Bh[8], Bl[8];
#pragma unroll
  for (int jt = 0; jt < 8; jt++) {
    int tile = h * 8 + jt;
#pragma unroll
    for (int j = 0; j < 8; j++) {
      float v = Wr[(quad * 8 + j) * K + tile * 16 + col];
      unsigned u = __float_as_uint(v);
      unsigned hb = u >> 16;
      float hf = __uint_as_float(hb << 16);
      unsigned lb = __float_as_uint(v - hf) >> 16;
      Bh[jt].u[j] = (unsigned short)hb;
      Bl[jt].u[j] = (unsigned short)lb;
    }
  }
  float acce[8], accx[8], accy[8], accz[8];
#pragma unroll
  for (int jt = 0; jt < 8; jt++) { acce[jt] = 0.f; accx[jt] = 0.f; accy[jt] = 0.f; accz[jt] = 0.f; }

#pragma unroll 1
  for (int nt = nh * 8; nt < nh * 8 + 8; nt++) {
    const float* fb = f + ((size_t)(pbase + nt * 16 + col)) * C + quad * 8;
    float4 a0 = *(const float4*)fb;
    float4 a1 = *(const float4*)(fb + 4);
    float av[8] = {a0.x, a0.y, a0.z, a0.w, a1.x, a1.y, a1.z, a1.w};
    U16x8 Ah, Al;
#pragma unroll
    for (int j = 0; j < 8; j++) {
      unsigned u = __float_as_uint(av[j]);
      unsigned hb = u >> 16;
      float hf = __uint_as_float(hb << 16);
      unsigned lb = __float_as_uint(av[j] - hf) >> 16;
      Ah.u[j] = (unsigned short)hb;
      Al.u[j] = (unsigned short)lb;
    }
    float4 pr0 = posLDS[nt * 16 + quad * 4 + 0];
    float4 pr1 = posLDS[nt * 16 + quad * 4 + 1];
    float4 pr2 = posLDS[nt * 16 + quad * 4 + 2];
    float4 pr3 = posLDS[nt * 16 + quad * 4 + 3];
#pragma unroll
    for (int jt = 0; jt < 8; jt++) {
      f32x4 d = {0.f, 0.f, 0.f, 0.f};
      d = __builtin_amdgcn_mfma_f32_16x16x32_bf16(Al.v, Bh[jt].v, d, 0, 0, 0);
      d = __builtin_amdgcn_mfma_f32_16x16x32_bf16(Ah.v, Bl[jt].v, d, 0, 0, 0);
      d = __builtin_amdgcn_mfma_f32_16x16x32_bf16(Ah.v, Bh[jt].v, d, 0, 0, 0);
      // C/D layout: col=lane&15 (kp), row=quad*4+reg (pt)  [m89-verified]
      float e0 = __expf(d[0]), e1 = __expf(d[1]), e2 = __expf(d[2]), e3 = __expf(d[3]);
      acce[jt] += (e0 + e1) + (e2 + e3);
      accx[jt] += e0 * pr0.x + e1 * pr1.x + e2 * pr2.x + e3 * pr3.x;
      accy[jt] += e0 * pr0.y + e1 * pr1.y + e2 * pr2.y + e3 * pr3.y;
      accz[jt] += e0 * pr0.z + e1 * pr1.z + e2 * pr2.z + e3 * pr3.z;
    }
  }

#pragma unroll
  for (int jt = 0; jt < 8; jt++) {
    acce[jt] += __shfl_xor(acce[jt], 16); acce[jt] += __shfl_xor(acce[jt], 32);
    accx[jt] += __shfl_xor(accx[jt], 16); accx[jt] += __shfl_xor(accx[jt], 32);
    accy[jt] += __shfl_xor(accy[jt], 16); accy[jt] += __shfl_xor(accy[jt], 32);
    accz[jt] += __shfl_xor(accz[jt], 16); accz[jt] += __shfl_xor(accz[jt], 32);
  }
  __syncthreads();
  if (lane < 16) {
#pragma unroll
    for (int jt = 0; jt < 8; jt++)
      fm[nh][h * 128 + jt * 16 + lane] = make_float4(acce[jt], accx[jt], accy[jt], accz[jt]);
  }
  __syncthreads();
  float4 v0 = fm[0][t], v1 = fm[1][t];
  float4* po = (float4*)partials;
  po[(size_t)blockIdx.x * 256 + t] =
      make_float4(v0.x + v1.x, v0.y + v1.y, v0.z + v1.z, v0.w + v1.w);
}

// ---------------------------------------------------------------------------
// Phase 2a (k_cand, grid=BS*8, 256 thr): each block REDUNDANTLY merges the
// full partial set of its graph (256 KiB, IF$-hot) -> keypoints (ch0 writes
// them out), centroid, maxdiam -- no inter-block communication. Then a
// BLOCK-LOCAL histogram over its own 2048 points gives T_b >= d16_local >=
// d16_global(centroid), so R_b = sqrt(T_b) + 2*maxdiam is a valid compaction
// radius (triangle-inequality superset; exact top-16 later is radius-
// independent). Compaction is LDS-first with a single global atomicAdd per
// block. Degenerate (bin overflow) -> R=inf -> ccnt>CAP -> topk full-scan
// fallback (always correct).
// ---------------------------------------------------------------------------
__global__ __launch_bounds__(256) void k_cand(
    const float* __restrict__ pos, const float* __restrict__ partials,
    float* __restrict__ kpts, unsigned* __restrict__ ccnt,
    float4* __restrict__ cand) {
  int g = blockIdx.x >> 3;
  int ch = blockIdx.x & 7;
  int t = threadIdx.x;
  int lane = t & 63, wave = t >> 6;

  __shared__ float kxs[256], kys[256], kzs[256];
  __shared__ float wred[4][4];
  __shared__ float bc[4];
  __shared__ unsigned hist[NBINS];
  __shared__ unsigned sc[NBINS];
  __shared__ int mbin;
  __shared__ unsigned lcnt, gbase;
  __shared__ float cxs[2048], cys[2048], czs[2048];
  __shared__ int cis[2048];

  hist[t] = 0; hist[t + 256] = 0;
  if (t == 0) { lcnt = 0; mbin = NBINS - 1; }

  // --- merge partials -> keypoint t (coalesced; 64 splits) ---
  {
    const float4* po = (const float4*)partials;
    float L = 0.f, X = 0.f, Y = 0.f, Z = 0.f;
#pragma unroll 8
    for (int s = 0; s < NSPL; s++) {
      float4 v = po[((size_t)(g * NSPL + s)) * 256 + t];
      L += v.x; X += v.y; Y += v.z; Z += v.w;
    }
    float inv = 1.f / L;
    float kx = X * inv, ky = Y * inv, kz = Z * inv;
    kxs[t] = kx; kys[t] = ky; kzs[t] = kz;
    if (ch == 0) ((float4*)kpts)[g * 256 + t] = make_float4(kx, ky, kz, 0.f);
  }
  __syncthreads();

  // --- centroid ---
  float sx = kxs[t], sy = kys[t], sz = kzs[t];
#pragma unroll
  for (int off = 32; off; off >>= 1) {
    sx += __shfl_xor(sx, off, 64);
    sy += __shfl_xor(sy, off, 64);
    sz += __shfl_xor(sz, off, 64);
  }
  if (lane == 0) { wred[wave][0] = sx; wred[wave][1] = sy; wred[wave][2] = sz; }
  __syncthreads();
  if (t == 0) {
    float X = 0.f, Y = 0.f, Z = 0.f;
#pragma unroll
    for (int i = 0; i < 4; i++) { X += wred[i][0]; Y += wred[i][1]; Z += wred[i][2]; }
    bc[0] = X / K; bc[1] = Y / K; bc[2] = Z / K;
  }
  __syncthreads();
  float cx = bc[0], cy = bc[1], cz = bc[2];

  // --- max keypoint distance from centroid ---
  {
    float dx = kxs[t] - cx, dy = kys[t] - cy, dz = kzs[t] - cz;
    float md = dx * dx + dy * dy + dz * dz;
#pragma unroll
    for (int off = 32; off; off >>= 1) md = fmaxf(md, __shfl_xor(md, off, 64));
    if (lane == 0) wred[wave][3] = md;
  }
  __syncthreads();
  if (t == 0) {
    float m = fmaxf(fmaxf(wred[0][3], wred[1][3]), fmaxf(wred[2][3], wred[3][3]));
    bc[3] = sqrtf(m);
  }
  __syncthreads();
  float maxd = bc[3];

  // --- local histogram over this block's 2048 points (register-cached) ---
  float pxr[8], pyr[8], pzr[8], pdr[8];
#pragma unroll
  for (int i = 0; i < 8; i++) {
    int pl = ch * 2048 + i * 256 + t;
    const float* pp = pos + (size_t)(g * NPTS + pl) * 3;
    pxr[i] = pp[0]; pyr[i] = pp[1]; pzr[i] = pp[2];
    float dx = pxr[i] - cx, dy = pyr[i] - cy, dz = pzr[i] - cz;
    pdr[i] = dx * dx + dy * dy + dz * dz;
    int bin = (int)(pdr[i] * (1.0f / BINW));
    if (bin < NBINS - 1) atomicAdd(&hist[bin], 1u);
  }
  __syncthreads();

  // --- parallel inclusive scan -> first bin with cum >= 16 ---
  sc[t] = hist[t]; sc[t + 256] = hist[t + 256];
  __syncthreads();
  for (int off = 1; off < NBINS; off <<= 1) {
    unsigned a0 = (t >= off) ? sc[t - off] : 0u;
    unsigned a1 = ((t + 256) >= off) ? sc[t + 256 - off] : 0u;
    __syncthreads();
    sc[t] += a0; sc[t + 256] += a1;
    __syncthreads();
  }
  {
    unsigned c0 = sc[t], p0 = t ? sc[t - 1] : 0u;
    unsigned c1 = sc[t + 256], p1 = sc[t + 255];
    if (c0 >= KNNK && p0 < KNNK) atomicMin(&mbin, t);
    if ((t + 256) < (NBINS - 1) && c1 >= KNNK && p1 < KNNK) atomicMin(&mbin, t + 256);
  }
  __syncthreads();
  float r2;
  if (mbin < NBINS - 1) {
    float Rf = sqrtf((mbin + 1) * BINW) + 2.f * maxd;
    r2 = Rf * Rf;
  } else r2 = 3.0e38f;

  // --- compact to LDS, one global atomic per block, bulk copy out ---
#pragma unroll
  for (int i = 0; i < 8; i++) {
    if (pdr[i] <= r2) {
      unsigned u = atomicAdd(&lcnt, 1u);   // u < 2048 always
      cxs[u] = pxr[i]; cys[u] = pyr[i]; czs[u] = pzr[i];
      cis[u] = ch * 2048 + i * 256 + t;
    }
  }
  __syncthreads();
  if (t == 0) gbase = atomicAdd(&ccnt[g], lcnt);
  __syncthreads();
  unsigned nl = lcnt, base = gbase;
  for (unsigned j = t; j < nl; j += 256) {
    unsigned dst = base + j;
    if (dst < CAP)
      cand[(size_t)g * CAP + dst] = make_float4(cxs[j], cys[j], czs[j], __int_as_float(cis[j]));
  }
}

// ---------------------------------------------------------------------------
// Phase 2b (k_topk_ext, grid=BS, 1024 thr): exact top-16 per keypoint over
// the LDS-staged candidate set (~230/graph); indices stay in LDS and feed the
// fused extract (gather 16 rows, mean, 32x32 linear). Overflow -> full scan.
// ---------------------------------------------------------------------------
__global__ __launch_bounds__(1024) void k_topk_ext(
    const float* __restrict__ pos, const float* __restrict__ f,
    const float* __restrict__ We, const float* __restrict__ kpts,
    const unsigned* __restrict__ ccnt, const float4* __restrict__ cand,
    float* __restrict__ out) {
  int g = blockIdx.x;
  int t = threadIdx.x;

  __shared__ float cxs[CAP], cys[CAP], czs[CAP];
  __shared__ int cis[CAP];
  __shared__ int nidx[256][KNNK];
  __shared__ float P[32][C + 1];
  __shared__ float WeL[C][C + 1];

  unsigned cnt = ccnt[g];
  int ovf = cnt > CAP;
  int n = ovf ? 0 : (int)cnt;
  for (int j = t; j < n; j += 1024) {
    float4 v = cand[(size_t)g * CAP + j];
    cxs[j] = v.x; cys[j] = v.y; czs[j] = v.z; cis[j] = __float_as_int(v.w);
  }
  WeL[t >> 5][t & 31] = We[t];   // C*C == 1024
  __syncthreads();

  if (t < 256) {
    float4 kpt = ((const float4*)kpts)[g * 256 + t];
    float kx = kpt.x, ky = kpt.y, kz = kpt.z;
    float dd[KNNK]; int ii[KNNK];
#pragma unroll
    for (int j = 0; j < KNNK; j++) { dd[j] = 1e30f; ii[j] = 0; }
    float mx = 1e30f;
    if (!ovf) {
      for (int j = 0; j < n; j++) {
        float dx = kx - cxs[j], dy = ky - cys[j], dz = kz - czs[j];
        float d2 = dx * dx + dy * dy + dz * dz;
        if (d2 < mx) {
          int sm = 0; float bv = dd[0];
#pragma unroll
          for (int s = 1; s < KNNK; s++) if (dd[s] > bv) { bv = dd[s]; sm = s; }
#pragma unroll
          for (int s = 0; s < KNNK; s++) if (s == sm) { dd[s] = d2; ii[s] = cis[j]; }
          mx = dd[0];
#pragma unroll
          for (int s = 1; s < KNNK; s++) mx = fmaxf(mx, dd[s]);
        }
      }
    } else {
      for (int j = 0; j < NPTS; j++) {
        const float* pp = pos + (size_t)(g * NPTS + j) * 3;
        float dx = kx - pp[0], dy = ky - pp[1], dz = kz - pp[2];
        float d2 = dx * dx + dy * dy + dz * dz;
        if (d2 < mx) {
          int sm = 0; float bv = dd[0];
#pragma unroll
          for (int s = 1; s < KNNK; s++) if (dd[s] > bv) { bv = dd[s]; sm = s; }
#pragma unroll
          for (int s = 0; s < KNNK; s++) if (s == sm) { dd[s] = d2; ii[s] = j; }
          mx = dd[0];
#pragma unroll
          for (int s = 1; s < KNNK; s++) mx = fmaxf(mx, dd[s]);
        }
      }
    }
#pragma unroll
    for (int j = 0; j < KNNK; j++) nidx[t][j] = ii[j];
  }
  __syncthreads();

  // --- fused extract: 1024 thr = 32 kp-slots x 32 channels, 8 iterations ---
  int c = t & 31, kl = t >> 5;
#pragma unroll 1
  for (int hh = 0; hh < 8; hh++) {
    int kp = hh * 32 + kl;
    float s = 0.f;
#pragma unroll
    for (int j = 0; j < KNNK; j++) {
      int pl = nidx[kp][j];
      s += f[((size_t)(g * NPTS + pl)) * C + c];
    }
    P[kl][c] = s * (1.f / KNNK);
    __syncthreads();
    float r = 0.f;
#pragma unroll
    for (int cc = 0; cc < C; cc++) r += P[kl][cc] * WeL[cc][c];
    out[((size_t)(g * K + kp)) * C + c] = r;
    __syncthreads();
  }
}

extern "C" void kernel_launch(void* const* d_in, const int* in_sizes, int n_in,
                              void* d_out, int out_size, void* d_ws, size_t ws_size,
                              hipStream_t stream) {
  const float* f   = (const float*)d_in[0];
  const float* pos = (const float*)d_in[1];
  // d_in[2] = W_pool: mathematically unused (bias cancels in segment softmax)
  const float* Wr  = (const float*)d_in[3];
  const float* We  = (const float*)d_in[4];
  float* out = (float*)d_out;

  char* ws = (char*)d_ws;
  float*    partials = (float*)(ws + 0);          // [512][256][4] f32 = 2 MiB
  float*    kpts     = (float*)(ws + 2097152);    // [8][256] float4 = 32 KiB
  unsigned* ccnt     = (unsigned*)(ws + 2129920); // [8] u32
  float4*   cand     = (float4*)(ws + 2130432);   // [8][4096] float4 = 512 KiB

  k_logits  <<<dim3(BS * NSPL), dim3(256),  0, stream>>>(f, pos, Wr, partials, ccnt);
  k_cand    <<<dim3(BS * 8),    dim3(256),  0, stream>>>(pos, partials, kpts, ccnt, cand);
  k_topk_ext<<<dim3(BS),        dim3(1024), 0, stream>>>(pos, f, We, kpts, ccnt, cand, out);
}

// Round 4
// 168.723 us; speedup vs baseline: 2.2324x; 2.2324x over previous
//
#include <hip/hip_runtime.h>
#include <math.h>

#define BS 8
#define NPTS 16384
#define C 32
#define K 256
#define KNNK 16
#define NBINS 512
#define BININV 128.0f     // d-space bins: bin = int(d * 128), range d < 4
#define BINW_D 0.0078125f // 1/128
#define CAP 4096
#define NSPL 64           // point-splits per graph in k_logits

typedef float f32x4 __attribute__((ext_vector_type(4)));
typedef __bf16 bf16x8 __attribute__((ext_vector_type(8)));
union U16x8 { int4 i; bf16x8 v; unsigned short u[8]; };

// ---------------------------------------------------------------------------
// Phase 1: MFMA logit GEMM + exp + weighted position accumulation.
// Split-bf16: L = A_lo*B_hi + A_hi*B_lo + A_hi*B_hi (fp32 MFMA accum);
// verified: identical KNN sets vs fp32 path. Pooling head (W_pool) unused:
// its logit term is constant over n and cancels in the per-graph softmax.
// Block 0 additionally zeroes ccnt (stream order makes it visible to k_cand).
// ---------------------------------------------------------------------------
__global__ __launch_bounds__(256, 2) void k_logits(
    const float* __restrict__ f, const float* __restrict__ pos,
    const float* __restrict__ Wr, float* __restrict__ partials,
    unsigned* __restrict__ ccnt) {
  int b = blockIdx.x >> 6;          // 64 blocks per graph
  int r = blockIdx.x & 63;
  int pbase = b * NPTS + r * 256;
  int t = threadIdx.x;
  int w = t >> 6, lane = t & 63;
  int h = w & 1, nh = w >> 1;
  int quad = lane >> 4, col = lane & 15;

  if (blockIdx.x == 0 && t < BS) ccnt[t] = 0;

  __shared__ float4 posLDS[256];
  __shared__ float4 fm[2][256];

  // stage pos chunk (256 pts x 12 B) -> padded float4 via LDS repack
  float* rawf = (float*)&fm[0][0];
  if (t < 192) ((float4*)rawf)[t] = ((const float4*)(pos + (size_t)pbase * 3))[t];
  __syncthreads();
  float4 myp = make_float4(rawf[t * 3], rawf[t * 3 + 1], rawf[t * 3 + 2], 0.f);
  __syncthreads();
  posLDS[t] = myp;

  // B fragments for this wave's kp-half (8 tiles), direct fp32 load + split.
  U16x8 Bh[8], Bl[8];
#pragma unroll
  for (int jt = 0; jt < 8; jt++) {
    int tile = h * 8 + jt;
#pragma unroll
    for (int j = 0; j < 8; j++) {
      float v = Wr[(quad * 8 + j) * K + tile * 16 + col];
      unsigned u = __float_as_uint(v);
      unsigned hb = u >> 16;
      float hf = __uint_as_float(hb << 16);
      unsigned lb = __float_as_uint(v - hf) >> 16;
      Bh[jt].u[j] = (unsigned short)hb;
      Bl[jt].u[j] = (unsigned short)lb;
    }
  }
  float acce[8], accx[8], accy[8], accz[8];
#pragma unroll
  for (int jt = 0; jt < 8; jt++) { acce[jt] = 0.f; accx[jt] = 0.f; accy[jt] = 0.f; accz[jt] = 0.f; }

#pragma unroll 1
  for (int nt = nh * 8; nt < nh * 8 + 8; nt++) {
    const float* fb = f + ((size_t)(pbase + nt * 16 + col)) * C + quad * 8;
    float4 a0 = *(const float4*)fb;
    float4 a1 = *(const float4*)(fb + 4);
    float av[8] = {a0.x, a0.y, a0.z, a0.w, a1.x, a1.y, a1.z, a1.w};
    U16x8 Ah, Al;
#pragma unroll
    for (int j = 0; j < 8; j++) {
      unsigned u = __float_as_uint(av[j]);
      unsigned hb = u >> 16;
      float hf = __uint_as_float(hb << 16);
      unsigned lb = __float_as_uint(av[j] - hf) >> 16;
      Ah.u[j] = (unsigned short)hb;
      Al.u[j] = (unsigned short)lb;
    }
    float4 pr0 = posLDS[nt * 16 + quad * 4 + 0];
    float4 pr1 = posLDS[nt * 16 + quad * 4 + 1];
    float4 pr2 = posLDS[nt * 16 + quad * 4 + 2];
    float4 pr3 = posLDS[nt * 16 + quad * 4 + 3];
#pragma unroll
    for (int jt = 0; jt < 8; jt++) {
      f32x4 d = {0.f, 0.f, 0.f, 0.f};
      d = __builtin_amdgcn_mfma_f32_16x16x32_bf16(Al.v, Bh[jt].v, d, 0, 0, 0);
      d = __builtin_amdgcn_mfma_f32_16x16x32_bf16(Ah.v, Bl[jt].v, d, 0, 0, 0);
      d = __builtin_amdgcn_mfma_f32_16x16x32_bf16(Ah.v, Bh[jt].v, d, 0, 0, 0);
      // C/D layout: col=lane&15 (kp), row=quad*4+reg (pt)  [m89-verified]
      float e0 = __expf(d[0]), e1 = __expf(d[1]), e2 = __expf(d[2]), e3 = __expf(d[3]);
      acce[jt] += (e0 + e1) + (e2 + e3);
      accx[jt] += e0 * pr0.x + e1 * pr1.x + e2 * pr2.x + e3 * pr3.x;
      accy[jt] += e0 * pr0.y + e1 * pr1.y + e2 * pr2.y + e3 * pr3.y;
      accz[jt] += e0 * pr0.z + e1 * pr1.z + e2 * pr2.z + e3 * pr3.z;
    }
  }

#pragma unroll
  for (int jt = 0; jt < 8; jt++) {
    acce[jt] += __shfl_xor(acce[jt], 16); acce[jt] += __shfl_xor(acce[jt], 32);
    accx[jt] += __shfl_xor(accx[jt], 16); accx[jt] += __shfl_xor(accx[jt], 32);
    accy[jt] += __shfl_xor(accy[jt], 16); accy[jt] += __shfl_xor(accy[jt], 32);
    accz[jt] += __shfl_xor(accz[jt], 16); accz[jt] += __shfl_xor(accz[jt], 32);
  }
  __syncthreads();
  if (lane < 16) {
#pragma unroll
    for (int jt = 0; jt < 8; jt++)
      fm[nh][h * 128 + jt * 16 + lane] = make_float4(acce[jt], accx[jt], accy[jt], accz[jt]);
  }
  __syncthreads();
  float4 v0 = fm[0][t], v1 = fm[1][t];
  float4* po = (float4*)partials;
  po[(size_t)blockIdx.x * 256 + t] =
      make_float4(v0.x + v1.x, v0.y + v1.y, v0.z + v1.z, v0.w + v1.w);
}

// ---------------------------------------------------------------------------
// Phase 2a (k_cand, grid=BS*8, 256 thr): each block REDUNDANTLY merges the
// full partial set of its graph (256 KiB, L2-hot) -> keypoints (ch0 writes
// them out), centroid, maxdiam -- no inter-block communication. Then a
// BLOCK-LOCAL histogram over its own 2048 points gives T_b >= d16_local >=
// d16_global(centroid), so R_b = T_b + 2*maxdiam is a valid compaction radius
// (triangle-inequality superset; exact top-16 later is radius-independent).
// Bins are over DISTANCE (d*128, range d<4, ~full N(0,1)^3 support): round 3
// binned d^2 with range d<0.36, leaving only ~25 in-range pts per 2048-pt
// block -> ~3%/block chance cum<16 -> r2=inf -> ccnt>CAP -> 305us full-scan
// fallback. With d-binning every local point is in range; slop is one bin
// width (0.008) vs the 2*maxdiam term. Compaction is LDS-first with a single
// global atomicAdd per block. Degenerate -> R=inf -> fallback (always correct).
// ---------------------------------------------------------------------------
__global__ __launch_bounds__(256) void k_cand(
    const float* __restrict__ pos, const float* __restrict__ partials,
    float* __restrict__ kpts, unsigned* __restrict__ ccnt,
    float4* __restrict__ cand) {
  int g = blockIdx.x >> 3;
  int ch = blockIdx.x & 7;
  int t = threadIdx.x;
  int lane = t & 63, wave = t >> 6;

  __shared__ float kxs[256], kys[256], kzs[256];
  __shared__ float wred[4][4];
  __shared__ float bc[4];
  __shared__ unsigned hist[NBINS];
  __shared__ unsigned sc[NBINS];
  __shared__ int mbin;
  __shared__ unsigned lcnt, gbase;
  __shared__ float cxs[2048], cys[2048], czs[2048];
  __shared__ int cis[2048];

  hist[t] = 0; hist[t + 256] = 0;
  if (t == 0) { lcnt = 0; mbin = NBINS - 1; }

  // --- merge partials -> keypoint t (coalesced; 64 splits) ---
  {
    const float4* po = (const float4*)partials;
    float L = 0.f, X = 0.f, Y = 0.f, Z = 0.f;
#pragma unroll 8
    for (int s = 0; s < NSPL; s++) {
      float4 v = po[((size_t)(g * NSPL + s)) * 256 + t];
      L += v.x; X += v.y; Y += v.z; Z += v.w;
    }
    float inv = 1.f / L;
    float kx = X * inv, ky = Y * inv, kz = Z * inv;
    kxs[t] = kx; kys[t] = ky; kzs[t] = kz;
    if (ch == 0) ((float4*)kpts)[g * 256 + t] = make_float4(kx, ky, kz, 0.f);
  }
  __syncthreads();

  // --- centroid ---
  float sx = kxs[t], sy = kys[t], sz = kzs[t];
#pragma unroll
  for (int off = 32; off; off >>= 1) {
    sx += __shfl_xor(sx, off, 64);
    sy += __shfl_xor(sy, off, 64);
    sz += __shfl_xor(sz, off, 64);
  }
  if (lane == 0) { wred[wave][0] = sx; wred[wave][1] = sy; wred[wave][2] = sz; }
  __syncthreads();
  if (t == 0) {
    float X = 0.f, Y = 0.f, Z = 0.f;
#pragma unroll
    for (int i = 0; i < 4; i++) { X += wred[i][0]; Y += wred[i][1]; Z += wred[i][2]; }
    bc[0] = X / K; bc[1] = Y / K; bc[2] = Z / K;
  }
  __syncthreads();
  float cx = bc[0], cy = bc[1], cz = bc[2];

  // --- max keypoint distance from centroid ---
  {
    float dx = kxs[t] - cx, dy = kys[t] - cy, dz = kzs[t] - cz;
    float md = dx * dx + dy * dy + dz * dz;
#pragma unroll
    for (int off = 32; off; off >>= 1) md = fmaxf(md, __shfl_xor(md, off, 64));
    if (lane == 0) wred[wave][3] = md;
  }
  __syncthreads();
  if (t == 0) {
    float m = fmaxf(fmaxf(wred[0][3], wred[1][3]), fmaxf(wred[2][3], wred[3][3]));
    bc[3] = sqrtf(m);
  }
  __syncthreads();
  float maxd = bc[3];

  // --- local histogram over this block's 2048 points (register-cached) ---
  float pxr[8], pyr[8], pzr[8], pdr[8];
#pragma unroll
  for (int i = 0; i < 8; i++) {
    int pl = ch * 2048 + i * 256 + t;
    const float* pp = pos + (size_t)(g * NPTS + pl) * 3;
    pxr[i] = pp[0]; pyr[i] = pp[1]; pzr[i] = pp[2];
    float dx = pxr[i] - cx, dy = pyr[i] - cy, dz = pzr[i] - cz;
    pdr[i] = dx * dx + dy * dy + dz * dz;
    int bin = (int)(sqrtf(pdr[i]) * BININV);
    if (bin < NBINS - 1) atomicAdd(&hist[bin], 1u);
  }
  __syncthreads();

  // --- parallel inclusive scan -> first bin with cum >= 16 ---
  sc[t] = hist[t]; sc[t + 256] = hist[t + 256];
  __syncthreads();
  for (int off = 1; off < NBINS; off <<= 1) {
    unsigned a0 = (t >= off) ? sc[t - off] : 0u;
    unsigned a1 = ((t + 256) >= off) ? sc[t + 256 - off] : 0u;
    __syncthreads();
    sc[t] += a0; sc[t + 256] += a1;
    __syncthreads();
  }
  {
    unsigned c0 = sc[t], p0 = t ? sc[t - 1] : 0u;
    unsigned c1 = sc[t + 256], p1 = sc[t + 255];
    if (c0 >= KNNK && p0 < KNNK) atomicMin(&mbin, t);
    if ((t + 256) < (NBINS - 1) && c1 >= KNNK && p1 < KNNK) atomicMin(&mbin, t + 256);
  }
  __syncthreads();
  float r2;
  if (mbin < NBINS - 1) {
    float Rf = (mbin + 1) * BINW_D + 2.f * maxd;
    r2 = Rf * Rf;
  } else r2 = 3.0e38f;

  // --- compact to LDS, one global atomic per block, bulk copy out ---
#pragma unroll
  for (int i = 0; i < 8; i++) {
    if (pdr[i] <= r2) {
      unsigned u = atomicAdd(&lcnt, 1u);   // u < 2048 always
      cxs[u] = pxr[i]; cys[u] = pyr[i]; czs[u] = pzr[i];
      cis[u] = ch * 2048 + i * 256 + t;
    }
  }
  __syncthreads();
  if (t == 0) gbase = atomicAdd(&ccnt[g], lcnt);
  __syncthreads();
  unsigned nl = lcnt, base = gbase;
  for (unsigned j = t; j < nl; j += 256) {
    unsigned dst = base + j;
    if (dst < CAP)
      cand[(size_t)g * CAP + dst] = make_float4(cxs[j], cys[j], czs[j], __int_as_float(cis[j]));
  }
}

// ---------------------------------------------------------------------------
// Phase 2b (k_topk_ext, grid=BS, 1024 thr): exact top-16 per keypoint over
// the LDS-staged candidate set (~350/graph); indices stay in LDS and feed the
// fused extract (gather 16 rows, mean, 32x32 linear). Overflow -> full scan.
// ---------------------------------------------------------------------------
__global__ __launch_bounds__(1024) void k_topk_ext(
    const float* __restrict__ pos, const float* __restrict__ f,
    const float* __restrict__ We, const float* __restrict__ kpts,
    const unsigned* __restrict__ ccnt, const float4* __restrict__ cand,
    float* __restrict__ out) {
  int g = blockIdx.x;
  int t = threadIdx.x;

  __shared__ float cxs[CAP], cys[CAP], czs[CAP];
  __shared__ int cis[CAP];
  __shared__ int nidx[256][KNNK];
  __shared__ float P[32][C + 1];
  __shared__ float WeL[C][C + 1];

  unsigned cnt = ccnt[g];
  int ovf = cnt > CAP;
  int n = ovf ? 0 : (int)cnt;
  for (int j = t; j < n; j += 1024) {
    float4 v = cand[(size_t)g * CAP + j];
    cxs[j] = v.x; cys[j] = v.y; czs[j] = v.z; cis[j] = __float_as_int(v.w);
  }
  WeL[t >> 5][t & 31] = We[t];   // C*C == 1024
  __syncthreads();

  if (t < 256) {
    float4 kpt = ((const float4*)kpts)[g * 256 + t];
    float kx = kpt.x, ky = kpt.y, kz = kpt.z;
    float dd[KNNK]; int ii[KNNK];
#pragma unroll
    for (int j = 0; j < KNNK; j++) { dd[j] = 1e30f; ii[j] = 0; }
    float mx = 1e30f;
    if (!ovf) {
      for (int j = 0; j < n; j++) {
        float dx = kx - cxs[j], dy = ky - cys[j], dz = kz - czs[j];
        float d2 = dx * dx + dy * dy + dz * dz;
        if (d2 < mx) {
          int sm = 0; float bv = dd[0];
#pragma unroll
          for (int s = 1; s < KNNK; s++) if (dd[s] > bv) { bv = dd[s]; sm = s; }
#pragma unroll
          for (int s = 0; s < KNNK; s++) if (s == sm) { dd[s] = d2; ii[s] = cis[j]; }
          mx = dd[0];
#pragma unroll
          for (int s = 1; s < KNNK; s++) mx = fmaxf(mx, dd[s]);
        }
      }
    } else {
      for (int j = 0; j < NPTS; j++) {
        const float* pp = pos + (size_t)(g * NPTS + j) * 3;
        float dx = kx - pp[0], dy = ky - pp[1], dz = kz - pp[2];
        float d2 = dx * dx + dy * dy + dz * dz;
        if (d2 < mx) {
          int sm = 0; float bv = dd[0];
#pragma unroll
          for (int s = 1; s < KNNK; s++) if (dd[s] > bv) { bv = dd[s]; sm = s; }
#pragma unroll
          for (int s = 0; s < KNNK; s++) if (s == sm) { dd[s] = d2; ii[s] = j; }
          mx = dd[0];
#pragma unroll
          for (int s = 1; s < KNNK; s++) mx = fmaxf(mx, dd[s]);
        }
      }
    }
#pragma unroll
    for (int j = 0; j < KNNK; j++) nidx[t][j] = ii[j];
  }
  __syncthreads();

  // --- fused extract: 1024 thr = 32 kp-slots x 32 channels, 8 iterations ---
  int c = t & 31, kl = t >> 5;
#pragma unroll 1
  for (int hh = 0; hh < 8; hh++) {
    int kp = hh * 32 + kl;
    float s = 0.f;
#pragma unroll
    for (int j = 0; j < KNNK; j++) {
      int pl = nidx[kp][j];
      s += f[((size_t)(g * NPTS + pl)) * C + c];
    }
    P[kl][c] = s * (1.f / KNNK);
    __syncthreads();
    float r = 0.f;
#pragma unroll
    for (int cc = 0; cc < C; cc++) r += P[kl][cc] * WeL[cc][c];
    out[((size_t)(g * K + kp)) * C + c] = r;
    __syncthreads();
  }
}

extern "C" void kernel_launch(void* const* d_in, const int* in_sizes, int n_in,
                              void* d_out, int out_size, void* d_ws, size_t ws_size,
                              hipStream_t stream) {
  const float* f   = (const float*)d_in[0];
  const float* pos = (const float*)d_in[1];
  // d_in[2] = W_pool: mathematically unused (bias cancels in segment softmax)
  const float* Wr  = (const float*)d_in[3];
  const float* We  = (const float*)d_in[4];
  float* out = (float*)d_out;

  char* ws = (char*)d_ws;
  float*    partials = (float*)(ws + 0);          // [512][256][4] f32 = 2 MiB
  float*    kpts     = (float*)(ws + 2097152);    // [8][256] float4 = 32 KiB
  unsigned* ccnt     = (unsigned*)(ws + 2129920); // [8] u32
  float4*   cand     = (float4*)(ws + 2130432);   // [8][4096] float4 = 512 KiB

  k_logits  <<<dim3(BS * NSPL), dim3(256),  0, stream>>>(f, pos, Wr, partials, ccnt);
  k_cand    <<<dim3(BS * 8),    dim3(256),  0, stream>>>(pos, partials, kpts, ccnt, cand);
  k_topk_ext<<<dim3(BS),        dim3(1024), 0, stream>>>(pos, f, We, kpts, ccnt, cand, out);
}

// Round 5
// 122.234 us; speedup vs baseline: 3.0815x; 1.3803x over previous
//
#include <hip/hip_runtime.h>
#include <math.h>

#define BS 8
#define NPTS 16384
#define C 32
#define K 256
#define KNNK 16
#define NBINS 512
#define BININV 128.0f     // d-space bins: bin = int(d * 128), range d < 4
#define BINW_D 0.0078125f // 1/128
#define CAP 4096
#define LDSCAP 2048       // LDS-stageable candidate limit in k_topk_ext
#define NSPL 64           // point-splits per graph in k_logits

typedef float f32x4 __attribute__((ext_vector_type(4)));
typedef __bf16 bf16x8 __attribute__((ext_vector_type(8)));
union U16x8 { int4 i; bf16x8 v; unsigned short u[8]; };

// ---------------------------------------------------------------------------
// Phase 1: MFMA logit GEMM + exp + weighted position accumulation.
// Split-bf16: L = A_lo*B_hi + A_hi*B_lo + A_hi*B_hi (fp32 MFMA accum);
// verified: identical KNN sets vs fp32 path. Pooling head (W_pool) unused:
// its logit term is constant over n and cancels in the per-graph softmax.
// Block 0 additionally zeroes ccnt (stream order makes it visible to k_cand).
// ---------------------------------------------------------------------------
__global__ __launch_bounds__(256, 2) void k_logits(
    const float* __restrict__ f, const float* __restrict__ pos,
    const float* __restrict__ Wr, float* __restrict__ partials,
    unsigned* __restrict__ ccnt) {
  int b = blockIdx.x >> 6;          // 64 blocks per graph
  int r = blockIdx.x & 63;
  int pbase = b * NPTS + r * 256;
  int t = threadIdx.x;
  int w = t >> 6, lane = t & 63;
  int h = w & 1, nh = w >> 1;
  int quad = lane >> 4, col = lane & 15;

  if (blockIdx.x == 0 && t < BS) ccnt[t] = 0;

  __shared__ float4 posLDS[256];
  __shared__ float4 fm[2][256];

  // stage pos chunk (256 pts x 12 B) -> padded float4 via LDS repack
  float* rawf = (float*)&fm[0][0];
  if (t < 192) ((float4*)rawf)[t] = ((const float4*)(pos + (size_t)pbase * 3))[t];
  __syncthreads();
  float4 myp = make_float4(rawf[t * 3], rawf[t * 3 + 1], rawf[t * 3 + 2], 0.f);
  __syncthreads();
  posLDS[t] = myp;

  // B fragments for this wave's kp-half (8 tiles), direct fp32 load + split.
  U16x8 Bh[8], Bl[8];
#pragma unroll
  for (int jt = 0; jt < 8; jt++) {
    int tile = h * 8 + jt;
#pragma unroll
    for (int j = 0; j < 8; j++) {
      float v = Wr[(quad * 8 + j) * K + tile * 16 + col];
      unsigned u = __float_as_uint(v);
      unsigned hb = u >> 16;
      float hf = __uint_as_float(hb << 16);
      unsigned lb = __float_as_uint(v - hf) >> 16;
      Bh[jt].u[j] = (unsigned short)hb;
      Bl[jt].u[j] = (unsigned short)lb;
    }
  }
  float acce[8], accx[8], accy[8], accz[8];
#pragma unroll
  for (int jt = 0; jt < 8; jt++) { acce[jt] = 0.f; accx[jt] = 0.f; accy[jt] = 0.f; accz[jt] = 0.f; }

#pragma unroll 1
  for (int nt = nh * 8; nt < nh * 8 + 8; nt++) {
    const float* fb = f + ((size_t)(pbase + nt * 16 + col)) * C + quad * 8;
    float4 a0 = *(const float4*)fb;
    float4 a1 = *(const float4*)(fb + 4);
    float av[8] = {a0.x, a0.y, a0.z, a0.w, a1.x, a1.y, a1.z, a1.w};
    U16x8 Ah, Al;
#pragma unroll
    for (int j = 0; j < 8; j++) {
      unsigned u = __float_as_uint(av[j]);
      unsigned hb = u >> 16;
      float hf = __uint_as_float(hb << 16);
      unsigned lb = __float_as_uint(av[j] - hf) >> 16;
      Ah.u[j] = (unsigned short)hb;
      Al.u[j] = (unsigned short)lb;
    }
    float4 pr0 = posLDS[nt * 16 + quad * 4 + 0];
    float4 pr1 = posLDS[nt * 16 + quad * 4 + 1];
    float4 pr2 = posLDS[nt * 16 + quad * 4 + 2];
    float4 pr3 = posLDS[nt * 16 + quad * 4 + 3];
#pragma unroll
    for (int jt = 0; jt < 8; jt++) {
      f32x4 d = {0.f, 0.f, 0.f, 0.f};
      d = __builtin_amdgcn_mfma_f32_16x16x32_bf16(Al.v, Bh[jt].v, d, 0, 0, 0);
      d = __builtin_amdgcn_mfma_f32_16x16x32_bf16(Ah.v, Bl[jt].v, d, 0, 0, 0);
      d = __builtin_amdgcn_mfma_f32_16x16x32_bf16(Ah.v, Bh[jt].v, d, 0, 0, 0);
      // C/D layout: col=lane&15 (kp), row=quad*4+reg (pt)  [m89-verified]
      float e0 = __expf(d[0]), e1 = __expf(d[1]), e2 = __expf(d[2]), e3 = __expf(d[3]);
      acce[jt] += (e0 + e1) + (e2 + e3);
      accx[jt] += e0 * pr0.x + e1 * pr1.x + e2 * pr2.x + e3 * pr3.x;
      accy[jt] += e0 * pr0.y + e1 * pr1.y + e2 * pr2.y + e3 * pr3.y;
      accz[jt] += e0 * pr0.z + e1 * pr1.z + e2 * pr2.z + e3 * pr3.z;
    }
  }

#pragma unroll
  for (int jt = 0; jt < 8; jt++) {
    acce[jt] += __shfl_xor(acce[jt], 16); acce[jt] += __shfl_xor(acce[jt], 32);
    accx[jt] += __shfl_xor(accx[jt], 16); accx[jt] += __shfl_xor(accx[jt], 32);
    accy[jt] += __shfl_xor(accy[jt], 16); accy[jt] += __shfl_xor(accy[jt], 32);
    accz[jt] += __shfl_xor(accz[jt], 16); accz[jt] += __shfl_xor(accz[jt], 32);
  }
  __syncthreads();
  if (lane < 16) {
#pragma unroll
    for (int jt = 0; jt < 8; jt++)
      fm[nh][h * 128 + jt * 16 + lane] = make_float4(acce[jt], accx[jt], accy[jt], accz[jt]);
  }
  __syncthreads();
  float4 v0 = fm[0][t], v1 = fm[1][t];
  float4* po = (float4*)partials;
  po[(size_t)blockIdx.x * 256 + t] =
      make_float4(v0.x + v1.x, v0.y + v1.y, v0.z + v1.z, v0.w + v1.w);
}

// ---------------------------------------------------------------------------
// Phase 2a (k_cand, grid=BS*8, 256 thr): each block REDUNDANTLY merges the
// full partial set of its graph (256 KiB, L2-hot) -> keypoints (ch0 writes
// them out), centroid, maxdiam -- no inter-block communication. Then a
// BLOCK-LOCAL histogram over its own 2048 points gives T_b >= d16_local >=
// d16_global(centroid), so R_b = T_b + 2*maxdiam is a valid compaction radius
// (triangle-inequality superset; exact top-16 later is radius-independent).
// Bins over DISTANCE (d*128, d<4 covers the N(0,1)^3 support). Compaction is
// LDS-first with one global atomicAdd per block. Degenerate -> R=inf ->
// overflow -> topk full-scan fallback (always correct).
// ---------------------------------------------------------------------------
__global__ __launch_bounds__(256) void k_cand(
    const float* __restrict__ pos, const float* __restrict__ partials,
    float* __restrict__ kpts, unsigned* __restrict__ ccnt,
    float4* __restrict__ cand) {
  int g = blockIdx.x >> 3;
  int ch = blockIdx.x & 7;
  int t = threadIdx.x;
  int lane = t & 63, wave = t >> 6;

  __shared__ float kxs[256], kys[256], kzs[256];
  __shared__ float wred[4][4];
  __shared__ float bc[4];
  __shared__ unsigned hist[NBINS];
  __shared__ unsigned sc[NBINS];
  __shared__ int mbin;
  __shared__ unsigned lcnt, gbase;
  __shared__ float cxs[2048], cys[2048], czs[2048];
  __shared__ int cis[2048];

  hist[t] = 0; hist[t + 256] = 0;
  if (t == 0) { lcnt = 0; mbin = NBINS - 1; }

  // --- merge partials -> keypoint t (coalesced; 64 splits) ---
  {
    const float4* po = (const float4*)partials;
    float L = 0.f, X = 0.f, Y = 0.f, Z = 0.f;
#pragma unroll 8
    for (int s = 0; s < NSPL; s++) {
      float4 v = po[((size_t)(g * NSPL + s)) * 256 + t];
      L += v.x; X += v.y; Y += v.z; Z += v.w;
    }
    float inv = 1.f / L;
    float kx = X * inv, ky = Y * inv, kz = Z * inv;
    kxs[t] = kx; kys[t] = ky; kzs[t] = kz;
    if (ch == 0) ((float4*)kpts)[g * 256 + t] = make_float4(kx, ky, kz, 0.f);
  }
  __syncthreads();

  // --- centroid ---
  float sx = kxs[t], sy = kys[t], sz = kzs[t];
#pragma unroll
  for (int off = 32; off; off >>= 1) {
    sx += __shfl_xor(sx, off, 64);
    sy += __shfl_xor(sy, off, 64);
    sz += __shfl_xor(sz, off, 64);
  }
  if (lane == 0) { wred[wave][0] = sx; wred[wave][1] = sy; wred[wave][2] = sz; }
  __syncthreads();
  if (t == 0) {
    float X = 0.f, Y = 0.f, Z = 0.f;
#pragma unroll
    for (int i = 0; i < 4; i++) { X += wred[i][0]; Y += wred[i][1]; Z += wred[i][2]; }
    bc[0] = X / K; bc[1] = Y / K; bc[2] = Z / K;
  }
  __syncthreads();
  float cx = bc[0], cy = bc[1], cz = bc[2];

  // --- max keypoint distance from centroid ---
  {
    float dx = kxs[t] - cx, dy = kys[t] - cy, dz = kzs[t] - cz;
    float md = dx * dx + dy * dy + dz * dz;
#pragma unroll
    for (int off = 32; off; off >>= 1) md = fmaxf(md, __shfl_xor(md, off, 64));
    if (lane == 0) wred[wave][3] = md;
  }
  __syncthreads();
  if (t == 0) {
    float m = fmaxf(fmaxf(wred[0][3], wred[1][3]), fmaxf(wred[2][3], wred[3][3]));
    bc[3] = sqrtf(m);
  }
  __syncthreads();
  float maxd = bc[3];

  // --- local histogram over this block's 2048 points (register-cached) ---
  float pxr[8], pyr[8], pzr[8], pdr[8];
#pragma unroll
  for (int i = 0; i < 8; i++) {
    int pl = ch * 2048 + i * 256 + t;
    const float* pp = pos + (size_t)(g * NPTS + pl) * 3;
    pxr[i] = pp[0]; pyr[i] = pp[1]; pzr[i] = pp[2];
    float dx = pxr[i] - cx, dy = pyr[i] - cy, dz = pzr[i] - cz;
    pdr[i] = dx * dx + dy * dy + dz * dz;
    int bin = (int)(sqrtf(pdr[i]) * BININV);
    if (bin < NBINS - 1) atomicAdd(&hist[bin], 1u);
  }
  __syncthreads();

  // --- parallel inclusive scan -> first bin with cum >= 16 ---
  sc[t] = hist[t]; sc[t + 256] = hist[t + 256];
  __syncthreads();
  for (int off = 1; off < NBINS; off <<= 1) {
    unsigned a0 = (t >= off) ? sc[t - off] : 0u;
    unsigned a1 = ((t + 256) >= off) ? sc[t + 256 - off] : 0u;
    __syncthreads();
    sc[t] += a0; sc[t + 256] += a1;
    __syncthreads();
  }
  {
    unsigned c0 = sc[t], p0 = t ? sc[t - 1] : 0u;
    unsigned c1 = sc[t + 256], p1 = sc[t + 255];
    if (c0 >= KNNK && p0 < KNNK) atomicMin(&mbin, t);
    if ((t + 256) < (NBINS - 1) && c1 >= KNNK && p1 < KNNK) atomicMin(&mbin, t + 256);
  }
  __syncthreads();
  float r2;
  if (mbin < NBINS - 1) {
    float Rf = (mbin + 1) * BINW_D + 2.f * maxd;
    r2 = Rf * Rf;
  } else r2 = 3.0e38f;

  // --- compact to LDS, one global atomic per block, bulk copy out ---
#pragma unroll
  for (int i = 0; i < 8; i++) {
    if (pdr[i] <= r2) {
      unsigned u = atomicAdd(&lcnt, 1u);   // u < 2048 always
      cxs[u] = pxr[i]; cys[u] = pyr[i]; czs[u] = pzr[i];
      cis[u] = ch * 2048 + i * 256 + t;
    }
  }
  __syncthreads();
  if (t == 0) gbase = atomicAdd(&ccnt[g], lcnt);
  __syncthreads();
  unsigned nl = lcnt, base = gbase;
  for (unsigned j = t; j < nl; j += 256) {
    unsigned dst = base + j;
    if (dst < CAP)
      cand[(size_t)g * CAP + dst] = make_float4(cxs[j], cys[j], czs[j], __int_as_float(cis[j]));
  }
}

// ---------------------------------------------------------------------------
// Phase 2b (k_topk_ext, grid=BS*8, 256 thr, 32 kp/block): round-4 post-mortem
// found VGPR_Count=52 -- __launch_bounds__(1024) capped the kernel at 64
// VGPRs, spilling dd[16]/ii[16] to scratch (the 79us mystery). Now 256 thr
// (no cap, regs stay resident) and 8 LANES PER KEYPOINT: each lane scans a
// j%8 stripe of the candidates into a private reg top-16, then 16 rounds of
// argmin-extract merge across the 8 lanes via shfl_xor butterflies. Key =
// (d2-bits<<32)|candidate-slot: unique -> deterministic owner, exact order,
// no runtime-indexed arrays. Fused extract (4 passes x 8 kp) unchanged in
// spirit. Overflow (cnt>LDSCAP) -> 8-way-split full scan (always correct).
// ---------------------------------------------------------------------------
__global__ __launch_bounds__(256) void k_topk_ext(
    const float* __restrict__ pos, const float* __restrict__ f,
    const float* __restrict__ We, const float* __restrict__ kpts,
    const unsigned* __restrict__ ccnt, const float4* __restrict__ cand,
    float* __restrict__ out) {
  int g = blockIdx.x >> 3;
  int sb = blockIdx.x & 7;     // 32 keypoints per block
  int t = threadIdx.x;
  int kp = t >> 3;             // 0..31
  int part = t & 7;

  __shared__ float cxs[LDSCAP], cys[LDSCAP], czs[LDSCAP];
  __shared__ int cis[LDSCAP];
  __shared__ int nidx[32][KNNK];
  __shared__ float P[8][C + 1];
  __shared__ float WeL[C][C + 1];

  unsigned cnt = ccnt[g];
  int ovf = cnt > LDSCAP;
  int n = ovf ? 0 : (int)cnt;
  for (int j = t; j < n; j += 256) {
    float4 v = cand[(size_t)g * CAP + j];
    cxs[j] = v.x; cys[j] = v.y; czs[j] = v.z; cis[j] = __float_as_int(v.w);
  }
#pragma unroll
  for (int i = 0; i < 4; i++) {
    int idx = t + i * 256;
    WeL[idx >> 5][idx & 31] = We[idx];
  }
  __syncthreads();

  float4 kpt = ((const float4*)kpts)[g * 256 + sb * 32 + kp];
  float kx = kpt.x, ky = kpt.y, kz = kpt.z;
  float dd[KNNK]; int ii[KNNK];
#pragma unroll
  for (int j = 0; j < KNNK; j++) { dd[j] = 1e30f; ii[j] = 0; }
  float mx = 1e30f;

  if (!ovf) {
    for (int j = part; j < n; j += 8) {
      float dx = kx - cxs[j], dy = ky - cys[j], dz = kz - czs[j];
      float d2 = dx * dx + dy * dy + dz * dz;
      if (d2 < mx) {
        int sm = 0; float bv = dd[0];
#pragma unroll
        for (int s = 1; s < KNNK; s++) if (dd[s] > bv) { bv = dd[s]; sm = s; }
#pragma unroll
        for (int s = 0; s < KNNK; s++) if (s == sm) { dd[s] = d2; ii[s] = j; }
        mx = dd[0];
#pragma unroll
        for (int s = 1; s < KNNK; s++) mx = fmaxf(mx, dd[s]);
      }
    }
  } else {
    for (int j = part; j < NPTS; j += 8) {
      const float* pp = pos + (size_t)(g * NPTS + j) * 3;
      float dx = kx - pp[0], dy = ky - pp[1], dz = kz - pp[2];
      float d2 = dx * dx + dy * dy + dz * dz;
      if (d2 < mx) {
        int sm = 0; float bv = dd[0];
#pragma unroll
        for (int s = 1; s < KNNK; s++) if (dd[s] > bv) { bv = dd[s]; sm = s; }
#pragma unroll
        for (int s = 0; s < KNNK; s++) if (s == sm) { dd[s] = d2; ii[s] = j; }
        mx = dd[0];
#pragma unroll
        for (int s = 1; s < KNNK; s++) mx = fmaxf(mx, dd[s]);
      }
    }
  }

  // --- 8-lane merge: 16 rounds of unique-key argmin extraction ---
#pragma unroll 1
  for (int r = 0; r < KNNK; r++) {
    float bv = dd[0]; int sm = 0;
#pragma unroll
    for (int s = 1; s < KNNK; s++) if (dd[s] < bv) { bv = dd[s]; sm = s; }
    int bi = 0;
#pragma unroll
    for (int s = 0; s < KNNK; s++) if (s == sm) bi = ii[s];
    unsigned khi = __float_as_uint(bv), klo = (unsigned)bi;
    unsigned whi = khi, wlo = klo;
#pragma unroll
    for (int off = 1; off < 8; off <<= 1) {
      unsigned h2 = __shfl_xor(whi, off, 64);
      unsigned l2 = __shfl_xor(wlo, off, 64);
      if (h2 < whi || (h2 == whi && l2 < wlo)) { whi = h2; wlo = l2; }
    }
    if (whi == khi && wlo == klo) {   // unique owner: retire this entry
#pragma unroll
      for (int s = 0; s < KNNK; s++) if (s == sm) dd[s] = 1e30f;
    }
    if (part == 0) {
      int jw = (int)wlo;
      nidx[kp][r] = ovf ? jw : cis[jw];
    }
  }
  __syncthreads();

  // --- fused extract: 4 passes of (8 kp x 32 channels) ---
  int c = t & 31, kl = t >> 5;
#pragma unroll 1
  for (int hh = 0; hh < 4; hh++) {
    int kk = hh * 8 + kl;
    float s = 0.f;
#pragma unroll
    for (int j = 0; j < KNNK; j++) {
      int pl = nidx[kk][j];
      s += f[((size_t)(g * NPTS + pl)) * C + c];
    }
    P[kl][c] = s * (1.f / KNNK);
    __syncthreads();
    float r = 0.f;
#pragma unroll
    for (int cc = 0; cc < C; cc++) r += P[kl][cc] * WeL[cc][c];
    out[((size_t)(g * K + sb * 32 + kk)) * C + c] = r;
    __syncthreads();
  }
}

extern "C" void kernel_launch(void* const* d_in, const int* in_sizes, int n_in,
                              void* d_out, int out_size, void* d_ws, size_t ws_size,
                              hipStream_t stream) {
  const float* f   = (const float*)d_in[0];
  const float* pos = (const float*)d_in[1];
  // d_in[2] = W_pool: mathematically unused (bias cancels in segment softmax)
  const float* Wr  = (const float*)d_in[3];
  const float* We  = (const float*)d_in[4];
  float* out = (float*)d_out;

  char* ws = (char*)d_ws;
  float*    partials = (float*)(ws + 0);          // [512][256][4] f32 = 2 MiB
  float*    kpts     = (float*)(ws + 2097152);    // [8][256] float4 = 32 KiB
  unsigned* ccnt     = (unsigned*)(ws + 2129920); // [8] u32
  float4*   cand     = (float4*)(ws + 2130432);   // [8][4096] float4 = 512 KiB

  k_logits  <<<dim3(BS * NSPL), dim3(256), 0, stream>>>(f, pos, Wr, partials, ccnt);
  k_cand    <<<dim3(BS * 8),    dim3(256), 0, stream>>>(pos, partials, kpts, ccnt, cand);
  k_topk_ext<<<dim3(BS * 8),    dim3(256), 0, stream>>>(pos, f, We, kpts, ccnt, cand, out);
}